// Round 2
// baseline (4684.857 us; speedup 1.0000x reference)
//
#include <hip/hip_runtime.h>
#include <cstdint>
#include <cstddef>

// ---------------------------------------------------------------------------
// Persistent-kernel seq2seq decoder: 2-layer LSTM (H=1024) + Luong dot attn.
// T=256 strictly sequential steps; one persistent kernel, 256 blocks x 1024
// threads (16 waves/block = 4 waves/SIMD -> latency hiding), hand-rolled grid
// barrier (1 block/CU guaranteed by __launch_bounds__(1024,4) VGPR cap).
//
// Per step, 4 phases separated by grid barriers:
//   A: layer-0 LSTM  gates0 = W_ih0*x + W_hh0*h0   (block owns 4 h-dims,
//      wave = one (dim,gate) pair -> 2 row-dots of 1024)
//   B: layer-1 LSTM  gates1 = W_ih1*h0' + W_hh1*h1
//   C: scores_s = enc[s]*h1'  and  y2_j = Wc2[j]*h1'  (wave = half-row)
//   D: cooperative softmax (1 score/thread, LDS reduce) +
//      attn_h = tanh( (sum_s e_s*MT[j,s])/sum_s e_s + y2_j + b_j ); x <- attn_h
// MT[j,s] = Wc1[j]*enc[s] precomputed once (block b owns rows 4b..4b+3 ->
// XCD-local). Softmax normalization folds into the MT matvec (numer/denom).
//
// Cross-block data (x, h0', h1', scores) moves via sc1 agent-scope RELAXED
// atomics; shared vectors are staged into LDS once per block per phase.
// ---------------------------------------------------------------------------

#define TSTEPS 256
#define HDIM   1024
#define NBLK   256
#define NTHR   1024

// float-index offsets into ws
#define WS_X    0        // x (attn_h feedback) [1024]
#define WS_H0   1024     // h0 double buffer [2][1024]
#define WS_H1   3072     // h1 double buffer [2][1024]
#define WS_C0   5120     // c0 [1024] (block-private slices)
#define WS_C1   6144     // c1 [1024]
#define WS_SC   7168     // scores [1024]
#define WS_MT   16384    // MT [1024][1024]
#define SLOTS_OFF_BYTES ((size_t)(WS_MT + 1024 * 1024) * sizeof(float))
#define SLOT_STRIDE 16   // ints (64 B apart)

__device__ __forceinline__ float wred_sum(float v) {
#pragma unroll
  for (int m = 32; m >= 1; m >>= 1) v += __shfl_xor(v, m, 64);
  return v;
}
__device__ __forceinline__ float wred_max(float v) {
#pragma unroll
  for (int m = 32; m >= 1; m >>= 1) v = fmaxf(v, __shfl_xor(v, m, 64));
  return v;
}

// agent-scope relaxed loads/stores (sc1: always at the coherence point)
__device__ __forceinline__ float aloadf(const float* p) {
  unsigned u = __hip_atomic_load((const unsigned*)(uintptr_t)p,
                                 __ATOMIC_RELAXED, __HIP_MEMORY_SCOPE_AGENT);
  return __uint_as_float(u);
}
__device__ __forceinline__ void astoref(float* p, float v) {
  __hip_atomic_store((unsigned*)p, __float_as_uint(v), __ATOMIC_RELAXED,
                     __HIP_MEMORY_SCOPE_AGENT);
}

// Symmetric grid barrier: block publishes monotone gen into its slot; threads
// 0..255 each poll one slot. Signed >= compare: 0xAAAAAAAA poison is negative
// (safe initial state) and later-generation overwrites can't deadlock.
__device__ __forceinline__ void gbar(int* slots, int gen) {
  __syncthreads();  // drains this block's outstanding (sc1) stores
  if (threadIdx.x == 0)
    __hip_atomic_store(&slots[blockIdx.x * SLOT_STRIDE], gen, __ATOMIC_RELAXED,
                       __HIP_MEMORY_SCOPE_AGENT);
  int ok = 1;
  do {
    if (threadIdx.x < NBLK) {
      int v = __hip_atomic_load(&slots[threadIdx.x * SLOT_STRIDE],
                                __ATOMIC_RELAXED, __HIP_MEMORY_SCOPE_AGENT);
      ok = (v >= gen);
      if (!ok) __builtin_amdgcn_s_sleep(2);
    }
  } while (!__syncthreads_and(ok));
}

__device__ __forceinline__ float sigmoidf_(float x) { return 1.f / (1.f + __expf(-x)); }

__global__ void __launch_bounds__(NTHR, 4) decoder_persist(
    const float* __restrict__ enc,   // [1024,1024]
    const float* __restrict__ hid,   // [2,1024]
    const float* __restrict__ cell,  // [2,1024]
    const float* __restrict__ w_ih,  // [2,4096,1024]
    const float* __restrict__ w_hh,  // [2,4096,1024]
    const float* __restrict__ b_ih,  // [2,4096]
    const float* __restrict__ b_hh,  // [2,4096]
    const float* __restrict__ wcat,  // [1024,2048]
    const float* __restrict__ bcat,  // [1024]
    float* __restrict__ out,         // [256,1024]
    float* __restrict__ ws) {
  const int b = blockIdx.x;
  const int tid = threadIdx.x;
  const int w = tid >> 6;   // wave 0..15
  const int l = tid & 63;   // lane
  int* slots = (int*)((char*)ws + SLOTS_OFF_BYTES);
  float* MT = ws + WS_MT;
  const int j0 = b << 2;

  __shared__ float sh_x[HDIM];          // staged input vector
  __shared__ float sh_h[HDIM];          // staged recurrent vector
  __shared__ __align__(16) float sh_es[HDIM];  // softmax e_s (phase D)
  __shared__ __align__(16) float sh_wc[4][HDIM]; // Wc1 rows (pre-phase only)
  __shared__ float sh_g[16];            // per-wave partials (gates / rows)
  __shared__ float sh_r[16];            // softmax max partials
  __shared__ float sh_p[16];            // softmax denom partials
  __shared__ float sh_q[16];            // numer partials
  __shared__ float sh_y2[4];            // y2 = Wc2 @ h1' (block's 4 dims)

  // ---- pre-phase: MT[j][s] = sum_h Wc1[j,h]*enc[s,h], block owns j=4b..4b+3
  {
    // stage the 4 Wc1 rows into LDS (coalesced)
#pragma unroll
    for (int rep = 0; rep < 4; ++rep)
      sh_wc[rep][tid & 1023] = wcat[(size_t)(j0 + rep) * 2048 + tid];
    // note: tid covers 0..1023; rep = row
    __syncthreads();
    const int s = (w << 6) + l;         // each lane owns one s
    const float* er = enc + (size_t)s * HDIM;
    float a0 = 0.f, a1 = 0.f, a2 = 0.f, a3 = 0.f;
    for (int hh = 0; hh < HDIM; hh += 4) {
      float4 ev = *(const float4*)(er + hh);
      float4 w0 = *(const float4*)&sh_wc[0][hh];  // LDS broadcast
      float4 w1 = *(const float4*)&sh_wc[1][hh];
      float4 w2 = *(const float4*)&sh_wc[2][hh];
      float4 w3 = *(const float4*)&sh_wc[3][hh];
      a0 += ev.x * w0.x + ev.y * w0.y + ev.z * w0.z + ev.w * w0.w;
      a1 += ev.x * w1.x + ev.y * w1.y + ev.z * w1.z + ev.w * w1.w;
      a2 += ev.x * w2.x + ev.y * w2.y + ev.z * w2.z + ev.w * w2.w;
      a3 += ev.x * w3.x + ev.y * w3.y + ev.z * w3.z + ev.w * w3.w;
    }
    MT[(size_t)(j0 + 0) * HDIM + s] = a0;   // coalesced stores (s = lane)
    MT[(size_t)(j0 + 1) * HDIM + s] = a1;
    MT[(size_t)(j0 + 2) * HDIM + s] = a2;
    MT[(size_t)(j0 + 3) * HDIM + s] = a3;
  }
  __syncthreads();  // MT consumed only by this block (phase D)

  const float* wih1 = w_ih + (size_t)4096 * 1024;
  const float* whh1 = w_hh + (size_t)4096 * 1024;
  const float* bih1 = b_ih + 4096;
  const float* bhh1 = b_hh + 4096;

  for (int t = 0; t < TSTEPS; ++t) {
    const int par = t & 1;
    float* h0r = ws + WS_H0 + par * 1024;
    float* h0w = ws + WS_H0 + (par ^ 1) * 1024;
    float* h1r = ws + WS_H1 + par * 1024;
    float* h1w = ws + WS_H1 + (par ^ 1) * 1024;

    // ===== Phase A: layer-0 LSTM. wave = (dim d = w>>2, gate g = w&3) =====
    {
      if (t == 0) {
        sh_x[tid] = hid[HDIM + tid];  // x0 = hidden_state[-1] (layer 1)
        sh_h[tid] = hid[tid];
      } else {
        sh_x[tid] = aloadf(ws + WS_X + tid);
        sh_h[tid] = aloadf(h0r + tid);
      }
      __syncthreads();
      const int d = w >> 2, g = w & 3, k = j0 + d;
      const float* wi = w_ih + (size_t)((g << 10) + k) * HDIM;
      const float* wh = w_hh + (size_t)((g << 10) + k) * HDIM;
      float p = 0.f;
#pragma unroll
      for (int i = 0; i < 8; ++i) {
        float2 wv = *(const float2*)(wi + 2 * l + 128 * i);
        float2 hv = *(const float2*)(wh + 2 * l + 128 * i);
        float2 xv = *(const float2*)(sh_x + 2 * l + 128 * i);
        float2 rv = *(const float2*)(sh_h + 2 * l + 128 * i);
        p += wv.x * xv.x + wv.y * xv.y + hv.x * rv.x + hv.y * rv.y;
      }
      p = wred_sum(p);
      if (l == 0) sh_g[w] = p;
      __syncthreads();
      if (tid < 4) {
        const int k2 = j0 + tid;
        float ig = sigmoidf_(sh_g[(tid << 2) + 0] + b_ih[k2] + b_hh[k2]);
        float fg = sigmoidf_(sh_g[(tid << 2) + 1] + b_ih[HDIM + k2] + b_hh[HDIM + k2]);
        float gg = tanhf   (sh_g[(tid << 2) + 2] + b_ih[2 * HDIM + k2] + b_hh[2 * HDIM + k2]);
        float og = sigmoidf_(sh_g[(tid << 2) + 3] + b_ih[3 * HDIM + k2] + b_hh[3 * HDIM + k2]);
        float cold = (t == 0) ? cell[k2] : ws[WS_C0 + k2];
        float cn = fg * cold + ig * gg;
        ws[WS_C0 + k2] = cn;                 // block-private
        astoref(h0w + k2, og * tanhf(cn));   // cross-block
      }
    }
    gbar(slots, t * 4 + 1);

    // ===== Phase B: layer-1 LSTM, input = h0', recurrent h1 =====
    {
      sh_x[tid] = aloadf(h0w + tid);
      if (t == 0) sh_h[tid] = hid[HDIM + tid];
      else        sh_h[tid] = aloadf(h1r + tid);
      __syncthreads();
      const int d = w >> 2, g = w & 3, k = j0 + d;
      const float* wi = wih1 + (size_t)((g << 10) + k) * HDIM;
      const float* wh = whh1 + (size_t)((g << 10) + k) * HDIM;
      float p = 0.f;
#pragma unroll
      for (int i = 0; i < 8; ++i) {
        float2 wv = *(const float2*)(wi + 2 * l + 128 * i);
        float2 hv = *(const float2*)(wh + 2 * l + 128 * i);
        float2 xv = *(const float2*)(sh_x + 2 * l + 128 * i);
        float2 rv = *(const float2*)(sh_h + 2 * l + 128 * i);
        p += wv.x * xv.x + wv.y * xv.y + hv.x * rv.x + hv.y * rv.y;
      }
      p = wred_sum(p);
      if (l == 0) sh_g[w] = p;
      __syncthreads();
      if (tid < 4) {
        const int k2 = j0 + tid;
        float ig = sigmoidf_(sh_g[(tid << 2) + 0] + bih1[k2] + bhh1[k2]);
        float fg = sigmoidf_(sh_g[(tid << 2) + 1] + bih1[HDIM + k2] + bhh1[HDIM + k2]);
        float gg = tanhf   (sh_g[(tid << 2) + 2] + bih1[2 * HDIM + k2] + bhh1[2 * HDIM + k2]);
        float og = sigmoidf_(sh_g[(tid << 2) + 3] + bih1[3 * HDIM + k2] + bhh1[3 * HDIM + k2]);
        float cold = (t == 0) ? cell[HDIM + k2] : ws[WS_C1 + k2];
        float cn = fg * cold + ig * gg;
        ws[WS_C1 + k2] = cn;
        astoref(h1w + k2, og * tanhf(cn));
      }
    }
    gbar(slots, t * 4 + 2);

    // ===== Phase C: scores (waves 0-7) and y2 (waves 8-15), wave = half-row =====
    {
      sh_x[tid] = aloadf(h1w + tid);
      __syncthreads();
      const int rw = w & 7;            // row-work index 0..7
      const int d = rw >> 1, half = rw & 1;
      const float* row = (w < 8)
          ? (enc  + (size_t)(j0 + d) * 1024 + half * 512)
          : (wcat + (size_t)(j0 + d) * 2048 + 1024 + half * 512);
      float p = 0.f;
#pragma unroll
      for (int i = 0; i < 4; ++i) {
        float2 wv = *(const float2*)(row + 2 * l + 128 * i);
        float2 xv = *(const float2*)(sh_x + half * 512 + 2 * l + 128 * i);
        p += wv.x * xv.x + wv.y * xv.y;
      }
      p = wred_sum(p);
      if (l == 0) sh_g[w] = p;
      __syncthreads();
      if (tid < 8) {
        if (tid < 4) {
          float sc = sh_g[2 * tid] + sh_g[2 * tid + 1];
          astoref(ws + WS_SC + j0 + tid, sc);          // cross-block
        } else {
          int d2 = tid - 4;
          sh_y2[d2] = sh_g[8 + 2 * d2] + sh_g[9 + 2 * d2];  // same-block (LDS)
        }
      }
    }
    gbar(slots, t * 4 + 3);

    // ===== Phase D: cooperative softmax + weighted-MT matvec + tanh =====
    {
      float sc = aloadf(ws + WS_SC + tid);   // 1 score per thread
      float m = wred_max(sc);
      if (l == 0) sh_r[w] = m;
      __syncthreads();
      float bm = sh_r[0];
#pragma unroll
      for (int i = 1; i < 16; ++i) bm = fmaxf(bm, sh_r[i]);
      float e = __expf(sc - bm);
      sh_es[tid] = e;
      float ps = wred_sum(e);
      if (l == 0) sh_p[w] = ps;
      __syncthreads();
      // numerator: wave = (dim d = w&3, s-chunk = w>>2 of 256)
      const int d = w & 3, chunk = w >> 2, k = j0 + d;
      const float* mrow = MT + (size_t)k * HDIM + (chunk << 8);
      float4 mv = *(const float4*)(mrow + 4 * l);
      float4 ev = *(const float4*)(&sh_es[(chunk << 8) + 4 * l]);
      float p = mv.x * ev.x + mv.y * ev.y + mv.z * ev.z + mv.w * ev.w;
      p = wred_sum(p);
      if (l == 0) sh_q[w] = p;
      __syncthreads();
      if (tid < 4) {
        const int k2 = j0 + tid;
        float denom = 0.f;
#pragma unroll
        for (int i = 0; i < 16; ++i) denom += sh_p[i];
        float numer = sh_q[tid] + sh_q[4 + tid] + sh_q[8 + tid] + sh_q[12 + tid];
        float a = tanhf(numer / denom + sh_y2[tid] + bcat[k2]);
        astoref(ws + WS_X + k2, a);          // next step's input
        out[(size_t)t * HDIM + k2] = a;      // kernel output
      }
    }
    gbar(slots, t * 4 + 4);
  }
}

extern "C" void kernel_launch(void* const* d_in, const int* in_sizes, int n_in,
                              void* d_out, int out_size, void* d_ws, size_t ws_size,
                              hipStream_t stream) {
  // d_in: 0 input_sequence (UNUSED by reference), 1 encoder_out, 2 hidden_state,
  //       3 cell_state, 4 w_ih, 5 w_hh, 6 b_ih, 7 b_hh, 8 w_concat, 9 b_concat
  const float* enc  = (const float*)d_in[1];
  const float* hid  = (const float*)d_in[2];
  const float* cel  = (const float*)d_in[3];
  const float* wih  = (const float*)d_in[4];
  const float* whh  = (const float*)d_in[5];
  const float* bih  = (const float*)d_in[6];
  const float* bhh  = (const float*)d_in[7];
  const float* wcat = (const float*)d_in[8];
  const float* bcat = (const float*)d_in[9];
  float* out = (float*)d_out;
  float* ws  = (float*)d_ws;

  hipLaunchKernelGGL(decoder_persist, dim3(NBLK), dim3(NTHR), 0, stream,
                     enc, hid, cel, wih, whh, bih, bhh, wcat, bcat, out, ws);
}